// Round 8
// baseline (159.469 us; speedup 1.0000x reference)
//
#include <hip/hip_runtime.h>
#include <math.h>

typedef unsigned short u16;
typedef unsigned int u32;
typedef __attribute__((ext_vector_type(8))) short bf16x8;
typedef __attribute__((ext_vector_type(4))) float f32x4;

#define HW32 1024
#define HW64 4096
#define KCAM 21
#define PB 32
#define PSPLIT 4

static __device__ __forceinline__ u16 f2bf(float x) {
  u32 u = __float_as_uint(x);
  u32 r = (u + 0x7FFFu + ((u >> 16) & 1u)) >> 16;
  return (u16)r;
}

// ---------------------------------------------------------------------------
// Kernel A: 1x1 convs at 32x32 (f32). grid (4 ptiles, 2 which x 2 jhalf, 8 n).
// ---------------------------------------------------------------------------
__global__ __launch_bounds__(256) void k_conv32(
    const float* __restrict__ aspp, const float* __restrict__ f3,
    const float* __restrict__ w_aspp, const float* __restrict__ w_f3,
    float* __restrict__ a32, float* __restrict__ g32)
{
  const int pt = blockIdx.x, which = blockIdx.y >> 1, jh = blockIdx.y & 1,
            n = blockIdx.z;
  const float* x = (which == 0 ? aspp : f3) + (size_t)n * 128 * HW32;
  const float* w = (which == 0 ? w_aspp : w_f3) + jh * 32 * 128;
  float* out = (which == 0 ? a32 : g32) + (size_t)n * 64 * HW32 + (size_t)jh * 32 * HW32;

  __shared__ __align__(16) float wlds[32 * 128];
  for (int i = threadIdx.x; i < 32 * 128; i += 256) wlds[i] = w[i];
  __syncthreads();

  const int p = pt * 256 + threadIdx.x;
  float acc[32];
#pragma unroll
  for (int j = 0; j < 32; ++j) acc[j] = 0.f;

  for (int c0 = 0; c0 < 128; c0 += 8) {
    float xv[8];
#pragma unroll
    for (int cc = 0; cc < 8; ++cc) xv[cc] = x[(size_t)(c0 + cc) * HW32 + p];
#pragma unroll
    for (int j = 0; j < 32; ++j) {
      const float4 w0 = *reinterpret_cast<const float4*>(&wlds[j * 128 + c0]);
      const float4 w1 = *reinterpret_cast<const float4*>(&wlds[j * 128 + c0 + 4]);
      acc[j] = fmaf(w0.x, xv[0], acc[j]);
      acc[j] = fmaf(w0.y, xv[1], acc[j]);
      acc[j] = fmaf(w0.z, xv[2], acc[j]);
      acc[j] = fmaf(w0.w, xv[3], acc[j]);
      acc[j] = fmaf(w1.x, xv[4], acc[j]);
      acc[j] = fmaf(w1.y, xv[5], acc[j]);
      acc[j] = fmaf(w1.z, xv[6], acc[j]);
      acc[j] = fmaf(w1.w, xv[7], acc[j]);
    }
  }
  for (int j = 0; j < 32; ++j) out[(size_t)j * HW32 + p] = acc[j];
}

// ---------------------------------------------------------------------------
// Kernel A2: camA[n][32][4096] bf16: rows 0..20 = cam, row 21 = 1.0, rest 0.
// ---------------------------------------------------------------------------
__global__ __launch_bounds__(256) void k_cam(
    const float* __restrict__ cam, u16* __restrict__ camA)
{
  const int idx = blockIdx.x * 256 + threadIdx.x;   // 8*32*4096 total
  const int n = idx >> 17;
  const int r = (idx >> 12) & 31;
  const int p = idx & 4095;
  float v = 0.f;
  if (r < KCAM) v = cam[((size_t)n * KCAM + r) * HW64 + p];
  else if (r == KCAM) v = 1.f;
  camA[idx] = f2bf(v);
}

// ---------------------------------------------------------------------------
// Kernel B: build normalized f as bf16 (RN) [n][pos][128].
// 512 threads (8 waves): group g=tid>>6 handles 16 output channels.
// ---------------------------------------------------------------------------
__global__ __launch_bounds__(512) void k_build_f(
    const float* __restrict__ inp, const float* __restrict__ a32,
    const float* __restrict__ g32, const float* __restrict__ w_f9,
    u16* __restrict__ fhi_g)
{
  const int y = blockIdx.x, n = blockIdx.y;

  __shared__ __align__(16) float wlds[128 * 132];
  __shared__ float feat[132 * 64];
  __shared__ float nrm[8][64];

  for (int i = threadIdx.x; i < 128 * 132; i += 512) wlds[i] = w_f9[i];

  const float s512 = 511.f / 63.f, s32 = 31.f / 63.f;
  const float syA = y * s512;
  const int y0A = (int)syA;
  const float wyA = syA - (float)y0A;
  const int y1A = min(y0A + 1, 511);
  const float syB = y * s32;
  const int y0B = (int)syB;
  const float wyB = syB - (float)y0B;
  const int y1B = min(y0B + 1, 31);

  for (int idx = threadIdx.x; idx < 132 * 64; idx += 512) {
    const int c = idx >> 6, x = idx & 63;
    float v;
    if (c < 4) {
      const float sx = x * s512;
      const int x0 = (int)sx;
      const float wx = sx - (float)x0;
      const int x1 = min(x0 + 1, 511);
      const float* im = inp + (size_t)(n * 4 + c) * 512 * 512;
      const float v00 = im[y0A * 512 + x0], v01 = im[y0A * 512 + x1];
      const float v10 = im[y1A * 512 + x0], v11 = im[y1A * 512 + x1];
      v = (v00 * (1.f - wx) + v01 * wx) * (1.f - wyA) +
          (v10 * (1.f - wx) + v11 * wx) * wyA;
    } else {
      const float* im = (c < 68) ? a32 + (size_t)(n * 64 + (c - 4)) * HW32
                                 : g32 + (size_t)(n * 64 + (c - 68)) * HW32;
      const float sx = x * s32;
      const int x0 = (int)sx;
      const float wx = sx - (float)x0;
      const int x1 = min(x0 + 1, 31);
      const float v00 = im[y0B * 32 + x0], v01 = im[y0B * 32 + x1];
      const float v10 = im[y1B * 32 + x0], v11 = im[y1B * 32 + x1];
      v = (v00 * (1.f - wx) + v01 * wx) * (1.f - wyB) +
          (v10 * (1.f - wx) + v11 * wx) * wyB;
    }
    feat[c * 64 + x] = v;
  }
  __syncthreads();

  const int x = threadIdx.x & 63;
  const int g = threadIdx.x >> 6;
  const int og = g * 16;

  float acc[16];
#pragma unroll
  for (int i = 0; i < 16; ++i) acc[i] = 0.f;

  for (int c0 = 0; c0 < 132; c0 += 4) {
    const float f0 = feat[(c0 + 0) * 64 + x];
    const float f1 = feat[(c0 + 1) * 64 + x];
    const float f2 = feat[(c0 + 2) * 64 + x];
    const float f3v = feat[(c0 + 3) * 64 + x];
#pragma unroll
    for (int i = 0; i < 16; ++i) {
      const float4 wv = *reinterpret_cast<const float4*>(&wlds[(og + i) * 132 + c0]);
      acc[i] = fmaf(wv.x, f0, acc[i]);
      acc[i] = fmaf(wv.y, f1, acc[i]);
      acc[i] = fmaf(wv.z, f2, acc[i]);
      acc[i] = fmaf(wv.w, f3v, acc[i]);
    }
  }

  float ss = 0.f;
#pragma unroll
  for (int i = 0; i < 16; ++i) ss = fmaf(acc[i], acc[i], ss);
  nrm[g][x] = ss;
  __syncthreads();
  float tot = 0.f;
#pragma unroll
  for (int gg = 0; gg < 8; ++gg) tot += nrm[gg][x];
  const float inv = 1.f / (sqrtf(tot) + 1e-5f);

  const size_t base = ((size_t)n * HW64 + (size_t)y * 64 + x) * 128 + og;
#pragma unroll
  for (int i = 0; i < 16; ++i) fhi_g[base + i] = f2bf(acc[i] * inv);
}

// ---------------------------------------------------------------------------
// Kernel C: fused affinity+cam, bf16 MFMA, NO LDS STAGING / NO BARRIERS.
// Stage-1 A-frags load straight from global (L1-shared across the block's
// 4 waves, L2-local via n->XCD swizzle). Stage-2 B-frags assembled intra-wave
// via ds_bpermute. Waves fully independent -> no lockstep drains.
// Block = 256 thr (4 waves; wave wq owns 64-wide q quarter). 256 q/block,
// p-range 1024 (PSPLIT=4), tiles of PB=32.
// grid 512 = 4ps x 16qt x 8n, n in low bits.
// part layout: [n][ps][22][4096]
// ---------------------------------------------------------------------------
__global__ __launch_bounds__(256) void k_fused(
    const u16* __restrict__ fhi_g, const u16* __restrict__ camA,
    float* __restrict__ part)
{
  const int gx = blockIdx.x;
  const int n = gx & 7;
  const int rest = gx >> 3;
  const int qt = rest & 15;
  const int ps = rest >> 4;
  const int tid = threadIdx.x;
  const int lane = tid & 63;
  const int wq = tid >> 6;
  const int l15 = lane & 15;
  const int l4 = lane >> 4;
  const int qb = qt * 256;

  const u16* fbase = fhi_g + (size_t)n * HW64 * 128;

  // q-side F fragments, resident in VGPRs (64 regs)
  bf16x8 Bq[4][4];
#pragma unroll
  for (int qf = 0; qf < 4; ++qf) {
    const size_t rowo = (size_t)(qb + wq * 64 + qf * 16 + l15) * 128;
#pragma unroll
    for (int s = 0; s < 4; ++s)
      Bq[qf][s] = *(const bf16x8*)(fbase + rowo + s * 32 + l4 * 8);
  }

  f32x4 nacc[2][4];
#pragma unroll
  for (int rt = 0; rt < 2; ++rt)
#pragma unroll
    for (int qf = 0; qf < 4; ++qf) nacc[rt][qf] = {0.f, 0.f, 0.f, 0.f};

  const int srcA4 = (((lane & 16) << 1) + l15) << 2;  // (32*(l4&1)+l15)*4
  const int srcB4 = srcA4 + 64;
  const bool hi = (l4 >= 2);

  const int p_base = ps * (HW64 / PSPLIT);
  for (int t = 0; t < (HW64 / PSPLIT) / PB; ++t) {   // 32 tiles
    const int p0 = p_base + t * PB;

    // ---- Stage 1: S C-frags, K=128; A-frags direct from global (L1/L2)
    f32x4 acc[2][4];
#pragma unroll
    for (int pf = 0; pf < 2; ++pf)
#pragma unroll
      for (int qf = 0; qf < 4; ++qf) acc[pf][qf] = {0.f, 0.f, 0.f, 0.f};

#pragma unroll
    for (int s = 0; s < 4; ++s) {
      bf16x8 Ah[2];
#pragma unroll
      for (int pf = 0; pf < 2; ++pf)
        Ah[pf] = *(const bf16x8*)(fbase + (size_t)(p0 + pf * 16 + l15) * 128 +
                                  s * 32 + l4 * 8);
#pragma unroll
      for (int pf = 0; pf < 2; ++pf)
#pragma unroll
        for (int qf = 0; qf < 4; ++qf)
          acc[pf][qf] = __builtin_amdgcn_mfma_f32_16x16x32_bf16(
              Ah[pf], Bq[qf][s], acc[pf][qf], 0, 0, 0);
    }

    // ---- relu + pack: P[pf][qf] = 2 dwords of bf16 pairs
    u32 P[2][4][2];
#pragma unroll
    for (int pf = 0; pf < 2; ++pf)
#pragma unroll
      for (int qf = 0; qf < 4; ++qf) {
        const float v0 = fmaxf(acc[pf][qf][0], 0.f);
        const float v1 = fmaxf(acc[pf][qf][1], 0.f);
        const float v2 = fmaxf(acc[pf][qf][2], 0.f);
        const float v3 = fmaxf(acc[pf][qf][3], 0.f);
        u32 d0, d1;
        asm("v_cvt_pk_bf16_f32 %0, %1, %2" : "=v"(d0) : "v"(v0), "v"(v1));
        asm("v_cvt_pk_bf16_f32 %0, %1, %2" : "=v"(d1) : "v"(v2), "v"(v3));
        P[pf][qf][0] = d0;
        P[pf][qf][1] = d1;
      }

    // ---- cam A-frags for this tile (bf16, L2-resident)
    bf16x8 Ac[2];
#pragma unroll
    for (int rt = 0; rt < 2; ++rt)
      Ac[rt] = *(const bf16x8*)(camA + ((size_t)n * 32 + rt * 16 + l15) * HW64 +
                                p0 + l4 * 8);

    // ---- Stage 2: B-frag assembly (intra-wave) + MFMA, K=32
#pragma unroll
    for (int qf = 0; qf < 4; ++qf) {
      const u32 w0a = (u32)__builtin_amdgcn_ds_bpermute(srcA4, (int)P[0][qf][0]);
      const u32 w0b = (u32)__builtin_amdgcn_ds_bpermute(srcA4, (int)P[1][qf][0]);
      const u32 w1a = (u32)__builtin_amdgcn_ds_bpermute(srcA4, (int)P[0][qf][1]);
      const u32 w1b = (u32)__builtin_amdgcn_ds_bpermute(srcA4, (int)P[1][qf][1]);
      const u32 w2a = (u32)__builtin_amdgcn_ds_bpermute(srcB4, (int)P[0][qf][0]);
      const u32 w2b = (u32)__builtin_amdgcn_ds_bpermute(srcB4, (int)P[1][qf][0]);
      const u32 w3a = (u32)__builtin_amdgcn_ds_bpermute(srcB4, (int)P[0][qf][1]);
      const u32 w3b = (u32)__builtin_amdgcn_ds_bpermute(srcB4, (int)P[1][qf][1]);
      union { u32 d[4]; bf16x8 v; } W;
      W.d[0] = hi ? w0b : w0a;
      W.d[1] = hi ? w1b : w1a;
      W.d[2] = hi ? w2b : w2a;
      W.d[3] = hi ? w3b : w3a;
      nacc[0][qf] = __builtin_amdgcn_mfma_f32_16x16x32_bf16(Ac[0], W.v, nacc[0][qf], 0, 0, 0);
      nacc[1][qf] = __builtin_amdgcn_mfma_f32_16x16x32_bf16(Ac[1], W.v, nacc[1][qf], 0, 0, 0);
    }
  }

  // ---- epilogue: rows = rt*16 + l4*4 + i (<22), cols = q
#pragma unroll
  for (int rt = 0; rt < 2; ++rt)
#pragma unroll
    for (int qf = 0; qf < 4; ++qf) {
      const int qg = qb + wq * 64 + qf * 16 + l15;
#pragma unroll
      for (int i = 0; i < 4; ++i) {
        const int row = rt * 16 + l4 * 4 + i;
        if (row < 22)
          part[(((size_t)n * PSPLIT + ps) * 22 + row) * HW64 + qg] = nacc[rt][qf][i];
      }
    }
}

// ---------------------------------------------------------------------------
// Kernel D: combine PSPLIT partials, divide.
// ---------------------------------------------------------------------------
__global__ __launch_bounds__(256) void k_final(
    const float* __restrict__ part, float* __restrict__ out, int total)
{
  const int idx = blockIdx.x * 256 + threadIdx.x;
  if (idx >= total) return;
  const int n = idx / (KCAM * HW64);
  const int r = idx - n * (KCAM * HW64);
  const int k = r >> 12;
  const int q = r & 4095;
  const float* base = part + (size_t)n * PSPLIT * 22 * HW64;
  float num = 0.f, den = 0.f;
#pragma unroll
  for (int p = 0; p < PSPLIT; ++p) {
    num += base[((size_t)p * 22 + k) * HW64 + q];
    den += base[((size_t)p * 22 + 21) * HW64 + q];
  }
  out[idx] = num / (den + 1e-5f);
}

// ---------------------------------------------------------------------------
extern "C" void kernel_launch(void* const* d_in, const int* in_sizes, int n_in,
                              void* d_out, int out_size, void* d_ws, size_t ws_size,
                              hipStream_t stream) {
  const float* aspp   = (const float*)d_in[0];
  const float* f3     = (const float*)d_in[1];
  const float* inp    = (const float*)d_in[2];
  const float* cam    = (const float*)d_in[3];
  const float* w_aspp = (const float*)d_in[4];
  const float* w_f3   = (const float*)d_in[5];
  const float* w_f9   = (const float*)d_in[6];
  float* out = (float*)d_out;

  // Workspace layout (~21.5 MB):
  //   [0, 8MB)        fhi  (u16, 8*4096*128)      written by k_build_f
  //   [8MB, 10MB)     camA (u16, 8*32*4096)       written by k_cam
  //   [10MB, 21.5MB)  part (f32, 8*4*22*4096)     written by k_fused
  //   a32/g32 (2MB each) ALIAS part's first 4MB: produced by k_conv32,
  //   consumed by k_build_f, dead before k_fused writes part (stream-ordered).
  u16*   fhi  = (u16*)d_ws;
  u16*   camA = fhi + 4194304;
  float* part = (float*)(camA + 1048576);
  float* a32  = part;
  float* g32  = a32 + 524288;

  k_conv32<<<dim3(4, 4, 8), 256, 0, stream>>>(aspp, f3, w_aspp, w_f3, a32, g32);
  k_cam<<<4096, 256, 0, stream>>>(cam, camA);
  k_build_f<<<dim3(64, 8), 512, 0, stream>>>(inp, a32, g32, w_f9, fhi);
  k_fused<<<512, 256, 0, stream>>>(fhi, camA, part);
  k_final<<<2688, 256, 0, stream>>>(part, out, 8 * KCAM * HW64);
}

// Round 9
// 139.022 us; speedup vs baseline: 1.1471x; 1.1471x over previous
//
#include <hip/hip_runtime.h>
#include <math.h>

typedef unsigned short u16;
typedef unsigned int u32;
typedef __attribute__((ext_vector_type(8))) short bf16x8;
typedef __attribute__((ext_vector_type(4))) short short4v;
typedef __attribute__((ext_vector_type(4))) float f32x4;

#define HW32 1024
#define HW64 4096
#define KCAM 21
#define PB 32
#define PSPLIT 4
#define FH_STR 136   // u16 LDS row stride (128 + 8 pad): 272B -> conflict-free b128

static __device__ __forceinline__ u16 f2bf(float x) {
  u32 u = __float_as_uint(x);
  u32 r = (u + 0x7FFFu + ((u >> 16) & 1u)) >> 16;
  return (u16)r;
}

// ---------------------------------------------------------------------------
// Kernel A: 1x1 convs at 32x32 (f32). grid (4 ptiles, 2 which x 2 jhalf, 8 n).
// ---------------------------------------------------------------------------
__global__ __launch_bounds__(256) void k_conv32(
    const float* __restrict__ aspp, const float* __restrict__ f3,
    const float* __restrict__ w_aspp, const float* __restrict__ w_f3,
    float* __restrict__ a32, float* __restrict__ g32)
{
  const int pt = blockIdx.x, which = blockIdx.y >> 1, jh = blockIdx.y & 1,
            n = blockIdx.z;
  const float* x = (which == 0 ? aspp : f3) + (size_t)n * 128 * HW32;
  const float* w = (which == 0 ? w_aspp : w_f3) + jh * 32 * 128;
  float* out = (which == 0 ? a32 : g32) + (size_t)n * 64 * HW32 + (size_t)jh * 32 * HW32;

  __shared__ __align__(16) float wlds[32 * 128];
  for (int i = threadIdx.x; i < 32 * 128; i += 256) wlds[i] = w[i];
  __syncthreads();

  const int p = pt * 256 + threadIdx.x;
  float acc[32];
#pragma unroll
  for (int j = 0; j < 32; ++j) acc[j] = 0.f;

  for (int c0 = 0; c0 < 128; c0 += 8) {
    float xv[8];
#pragma unroll
    for (int cc = 0; cc < 8; ++cc) xv[cc] = x[(size_t)(c0 + cc) * HW32 + p];
#pragma unroll
    for (int j = 0; j < 32; ++j) {
      const float4 w0 = *reinterpret_cast<const float4*>(&wlds[j * 128 + c0]);
      const float4 w1 = *reinterpret_cast<const float4*>(&wlds[j * 128 + c0 + 4]);
      acc[j] = fmaf(w0.x, xv[0], acc[j]);
      acc[j] = fmaf(w0.y, xv[1], acc[j]);
      acc[j] = fmaf(w0.z, xv[2], acc[j]);
      acc[j] = fmaf(w0.w, xv[3], acc[j]);
      acc[j] = fmaf(w1.x, xv[4], acc[j]);
      acc[j] = fmaf(w1.y, xv[5], acc[j]);
      acc[j] = fmaf(w1.z, xv[6], acc[j]);
      acc[j] = fmaf(w1.w, xv[7], acc[j]);
    }
  }
  for (int j = 0; j < 32; ++j) out[(size_t)j * HW32 + p] = acc[j];
}

// ---------------------------------------------------------------------------
// Kernel A2: camA[n][32][4096] bf16: rows 0..20 = cam, row 21 = 1.0, rest 0.
// ---------------------------------------------------------------------------
__global__ __launch_bounds__(256) void k_cam(
    const float* __restrict__ cam, u16* __restrict__ camA)
{
  const int idx = blockIdx.x * 256 + threadIdx.x;   // 8*32*4096 total
  const int n = idx >> 17;
  const int r = (idx >> 12) & 31;
  const int p = idx & 4095;
  float v = 0.f;
  if (r < KCAM) v = cam[((size_t)n * KCAM + r) * HW64 + p];
  else if (r == KCAM) v = 1.f;
  camA[idx] = f2bf(v);
}

// ---------------------------------------------------------------------------
// Kernel B: build normalized f as bf16 (RN) [n][pos][128].
// 512 threads (8 waves): group g=tid>>6 handles 16 output channels.
// ---------------------------------------------------------------------------
__global__ __launch_bounds__(512) void k_build_f(
    const float* __restrict__ inp, const float* __restrict__ a32,
    const float* __restrict__ g32, const float* __restrict__ w_f9,
    u16* __restrict__ fhi_g)
{
  const int y = blockIdx.x, n = blockIdx.y;

  __shared__ __align__(16) float wlds[128 * 132];
  __shared__ float feat[132 * 64];
  __shared__ float nrm[8][64];

  for (int i = threadIdx.x; i < 128 * 132; i += 512) wlds[i] = w_f9[i];

  const float s512 = 511.f / 63.f, s32 = 31.f / 63.f;
  const float syA = y * s512;
  const int y0A = (int)syA;
  const float wyA = syA - (float)y0A;
  const int y1A = min(y0A + 1, 511);
  const float syB = y * s32;
  const int y0B = (int)syB;
  const float wyB = syB - (float)y0B;
  const int y1B = min(y0B + 1, 31);

  for (int idx = threadIdx.x; idx < 132 * 64; idx += 512) {
    const int c = idx >> 6, x = idx & 63;
    float v;
    if (c < 4) {
      const float sx = x * s512;
      const int x0 = (int)sx;
      const float wx = sx - (float)x0;
      const int x1 = min(x0 + 1, 511);
      const float* im = inp + (size_t)(n * 4 + c) * 512 * 512;
      const float v00 = im[y0A * 512 + x0], v01 = im[y0A * 512 + x1];
      const float v10 = im[y1A * 512 + x0], v11 = im[y1A * 512 + x1];
      v = (v00 * (1.f - wx) + v01 * wx) * (1.f - wyA) +
          (v10 * (1.f - wx) + v11 * wx) * wyA;
    } else {
      const float* im = (c < 68) ? a32 + (size_t)(n * 64 + (c - 4)) * HW32
                                 : g32 + (size_t)(n * 64 + (c - 68)) * HW32;
      const float sx = x * s32;
      const int x0 = (int)sx;
      const float wx = sx - (float)x0;
      const int x1 = min(x0 + 1, 31);
      const float v00 = im[y0B * 32 + x0], v01 = im[y0B * 32 + x1];
      const float v10 = im[y1B * 32 + x0], v11 = im[y1B * 32 + x1];
      v = (v00 * (1.f - wx) + v01 * wx) * (1.f - wyB) +
          (v10 * (1.f - wx) + v11 * wx) * wyB;
    }
    feat[c * 64 + x] = v;
  }
  __syncthreads();

  const int x = threadIdx.x & 63;
  const int g = threadIdx.x >> 6;
  const int og = g * 16;

  float acc[16];
#pragma unroll
  for (int i = 0; i < 16; ++i) acc[i] = 0.f;

  for (int c0 = 0; c0 < 132; c0 += 4) {
    const float f0 = feat[(c0 + 0) * 64 + x];
    const float f1 = feat[(c0 + 1) * 64 + x];
    const float f2 = feat[(c0 + 2) * 64 + x];
    const float f3v = feat[(c0 + 3) * 64 + x];
#pragma unroll
    for (int i = 0; i < 16; ++i) {
      const float4 wv = *reinterpret_cast<const float4*>(&wlds[(og + i) * 132 + c0]);
      acc[i] = fmaf(wv.x, f0, acc[i]);
      acc[i] = fmaf(wv.y, f1, acc[i]);
      acc[i] = fmaf(wv.z, f2, acc[i]);
      acc[i] = fmaf(wv.w, f3v, acc[i]);
    }
  }

  float ss = 0.f;
#pragma unroll
  for (int i = 0; i < 16; ++i) ss = fmaf(acc[i], acc[i], ss);
  nrm[g][x] = ss;
  __syncthreads();
  float tot = 0.f;
#pragma unroll
  for (int gg = 0; gg < 8; ++gg) tot += nrm[gg][x];
  const float inv = 1.f / (sqrtf(tot) + 1e-5f);

  const size_t base = ((size_t)n * HW64 + (size_t)y * 64 + x) * 128 + og;
#pragma unroll
  for (int i = 0; i < 16; ++i) fhi_g[base + i] = f2bf(acc[i] * inv);
}

// ---------------------------------------------------------------------------
// Kernel C: fused affinity+cam, bf16 MFMA, ZERO-SHUFFLE stage-2.
// Key idea: MFMA contraction is invariant under a k-axis permutation applied
// to BOTH operands. With sigma(k = l4*8+j) = (j>>2)*16 + l4*4 + (j&3), the
// stage-2 B-fragment each lane needs is exactly its own stage-1 C-fragment
// registers (relu+cvt_pk, no bpermute/LDS), and cam's A-fragment absorbs
// sigma as two contiguous b64 loads per rt.
// Block = 256 thr (4 waves; wave wq owns 64-wide q quarter). 256 q/block,
// p-range 1024 (PSPLIT=4), tiles of PB=32. grid 512 = 4ps x 16qt x 8n.
// part layout: [n][ps][22][4096]
// ---------------------------------------------------------------------------
__global__ __launch_bounds__(256) void k_fused(
    const u16* __restrict__ fhi_g, const u16* __restrict__ camA,
    float* __restrict__ part)
{
  __shared__ __align__(16) u16 fh[PB * FH_STR];   // 8.7 KB

  const int gx = blockIdx.x;
  const int n = gx & 7;
  const int rest = gx >> 3;
  const int qt = rest & 15;
  const int ps = rest >> 4;
  const int tid = threadIdx.x;
  const int lane = tid & 63;
  const int wq = tid >> 6;
  const int l15 = lane & 15;
  const int l4 = lane >> 4;
  const int qb = qt * 256;

  // q-side F fragments, resident in VGPRs (64 regs)
  bf16x8 Bq[4][4];
#pragma unroll
  for (int qf = 0; qf < 4; ++qf) {
    const size_t rowo = ((size_t)n * HW64 + qb + wq * 64 + qf * 16 + l15) * 128;
#pragma unroll
    for (int s = 0; s < 4; ++s)
      Bq[qf][s] = *(const bf16x8*)(fhi_g + rowo + s * 32 + l4 * 8);
  }

  f32x4 nacc[2][4];
#pragma unroll
  for (int rt = 0; rt < 2; ++rt)
#pragma unroll
    for (int qf = 0; qf < 4; ++qf) nacc[rt][qf] = {0.f, 0.f, 0.f, 0.f};

  const int p_base = ps * (HW64 / PSPLIT);
  for (int t = 0; t < (HW64 / PSPLIT) / PB; ++t) {   // 32 tiles
    const int p0 = p_base + t * PB;
    __syncthreads();
    {   // stage F-tile: 32 rows x 128 ch bf16 (8 KB)
      const int p = tid >> 3;
      const int c = (tid & 7) * 16;
      const u16* src = fhi_g + ((size_t)n * HW64 + p0 + p) * 128 + c;
      *(bf16x8*)&fh[p * FH_STR + c] = *(const bf16x8*)src;
      *(bf16x8*)&fh[p * FH_STR + c + 8] = *(const bf16x8*)(src + 8);
    }
    __syncthreads();

    // ---- Stage 1: S C-frags, K=128
    f32x4 acc[2][4];
#pragma unroll
    for (int pf = 0; pf < 2; ++pf)
#pragma unroll
      for (int qf = 0; qf < 4; ++qf) acc[pf][qf] = {0.f, 0.f, 0.f, 0.f};

#pragma unroll
    for (int s = 0; s < 4; ++s) {
      bf16x8 Ah[2];
#pragma unroll
      for (int pf = 0; pf < 2; ++pf)
        Ah[pf] = *(const bf16x8*)&fh[(pf * 16 + l15) * FH_STR + s * 32 + l4 * 8];
#pragma unroll
      for (int pf = 0; pf < 2; ++pf)
#pragma unroll
        for (int qf = 0; qf < 4; ++qf)
          acc[pf][qf] = __builtin_amdgcn_mfma_f32_16x16x32_bf16(
              Ah[pf], Bq[qf][s], acc[pf][qf], 0, 0, 0);
    }

    // ---- cam A-frags under sigma: elem j<4 -> camA[r][p0+l4*4+j],
    //      elem j>=4 -> camA[r][p0+16+l4*4+(j-4)]  (two b64 loads per rt)
    bf16x8 Ac[2];
#pragma unroll
    for (int rt = 0; rt < 2; ++rt) {
      union { short4v h[2]; bf16x8 v; } A;
      const u16* cp = camA + ((size_t)n * 32 + rt * 16 + l15) * HW64 + p0 + l4 * 4;
      A.h[0] = *(const short4v*)cp;
      A.h[1] = *(const short4v*)(cp + 16);
      Ac[rt] = A.v;
    }

    // ---- Stage 2: B-frag = own C-frag regs (relu+pack), MFMA K=32
#pragma unroll
    for (int qf = 0; qf < 4; ++qf) {
      const float v0 = fmaxf(acc[0][qf][0], 0.f);
      const float v1 = fmaxf(acc[0][qf][1], 0.f);
      const float v2 = fmaxf(acc[0][qf][2], 0.f);
      const float v3 = fmaxf(acc[0][qf][3], 0.f);
      const float v4 = fmaxf(acc[1][qf][0], 0.f);
      const float v5 = fmaxf(acc[1][qf][1], 0.f);
      const float v6 = fmaxf(acc[1][qf][2], 0.f);
      const float v7 = fmaxf(acc[1][qf][3], 0.f);
      union { u32 d[4]; bf16x8 v; } W;
      asm("v_cvt_pk_bf16_f32 %0, %1, %2" : "=v"(W.d[0]) : "v"(v0), "v"(v1));
      asm("v_cvt_pk_bf16_f32 %0, %1, %2" : "=v"(W.d[1]) : "v"(v2), "v"(v3));
      asm("v_cvt_pk_bf16_f32 %0, %1, %2" : "=v"(W.d[2]) : "v"(v4), "v"(v5));
      asm("v_cvt_pk_bf16_f32 %0, %1, %2" : "=v"(W.d[3]) : "v"(v6), "v"(v7));
      nacc[0][qf] = __builtin_amdgcn_mfma_f32_16x16x32_bf16(Ac[0], W.v, nacc[0][qf], 0, 0, 0);
      nacc[1][qf] = __builtin_amdgcn_mfma_f32_16x16x32_bf16(Ac[1], W.v, nacc[1][qf], 0, 0, 0);
    }
  }

  // ---- epilogue: rows = rt*16 + l4*4 + i (<22), cols = q
#pragma unroll
  for (int rt = 0; rt < 2; ++rt)
#pragma unroll
    for (int qf = 0; qf < 4; ++qf) {
      const int qg = qb + wq * 64 + qf * 16 + l15;
#pragma unroll
      for (int i = 0; i < 4; ++i) {
        const int row = rt * 16 + l4 * 4 + i;
        if (row < 22)
          part[(((size_t)n * PSPLIT + ps) * 22 + row) * HW64 + qg] = nacc[rt][qf][i];
      }
    }
}

// ---------------------------------------------------------------------------
// Kernel D: combine PSPLIT partials, divide.
// ---------------------------------------------------------------------------
__global__ __launch_bounds__(256) void k_final(
    const float* __restrict__ part, float* __restrict__ out, int total)
{
  const int idx = blockIdx.x * 256 + threadIdx.x;
  if (idx >= total) return;
  const int n = idx / (KCAM * HW64);
  const int r = idx - n * (KCAM * HW64);
  const int k = r >> 12;
  const int q = r & 4095;
  const float* base = part + (size_t)n * PSPLIT * 22 * HW64;
  float num = 0.f, den = 0.f;
#pragma unroll
  for (int p = 0; p < PSPLIT; ++p) {
    num += base[((size_t)p * 22 + k) * HW64 + q];
    den += base[((size_t)p * 22 + 21) * HW64 + q];
  }
  out[idx] = num / (den + 1e-5f);
}

// ---------------------------------------------------------------------------
extern "C" void kernel_launch(void* const* d_in, const int* in_sizes, int n_in,
                              void* d_out, int out_size, void* d_ws, size_t ws_size,
                              hipStream_t stream) {
  const float* aspp   = (const float*)d_in[0];
  const float* f3     = (const float*)d_in[1];
  const float* inp    = (const float*)d_in[2];
  const float* cam    = (const float*)d_in[3];
  const float* w_aspp = (const float*)d_in[4];
  const float* w_f3   = (const float*)d_in[5];
  const float* w_f9   = (const float*)d_in[6];
  float* out = (float*)d_out;

  // Workspace layout (~21.5 MB):
  //   [0, 8MB)        fhi  (u16, 8*4096*128)      written by k_build_f
  //   [8MB, 10MB)     camA (u16, 8*32*4096)       written by k_cam
  //   [10MB, 21.5MB)  part (f32, 8*4*22*4096)     written by k_fused
  //   a32/g32 (2MB each) ALIAS part's first 4MB: produced by k_conv32,
  //   consumed by k_build_f, dead before k_fused writes part (stream-ordered).
  u16*   fhi  = (u16*)d_ws;
  u16*   camA = fhi + 4194304;
  float* part = (float*)(camA + 1048576);
  float* a32  = part;
  float* g32  = a32 + 524288;

  k_conv32<<<dim3(4, 4, 8), 256, 0, stream>>>(aspp, f3, w_aspp, w_f3, a32, g32);
  k_cam<<<4096, 256, 0, stream>>>(cam, camA);
  k_build_f<<<dim3(64, 8), 512, 0, stream>>>(inp, a32, g32, w_f9, fhi);
  k_fused<<<512, 256, 0, stream>>>(fhi, camA, part);
  k_final<<<2688, 256, 0, stream>>>(part, out, 8 * KCAM * HW64);
}